// Round 3
// baseline (218.068 us; speedup 1.0000x reference)
//
#include <hip/hip_runtime.h>
#include <hip/hip_cooperative_groups.h>

namespace cg = cooperative_groups;

#define D 256
#define S 128
#define B 32

typedef __attribute__((ext_vector_type(8))) short bf16x8;
typedef __attribute__((ext_vector_type(4))) float f32x4;

__device__ __forceinline__ unsigned short f2bf(float f) {
    union { float f; unsigned u; } v; v.f = f;
    unsigned r = v.u + 0x7FFFu + ((v.u >> 16) & 1u);   // RNE
    return (unsigned short)(r >> 16);
}
__device__ __forceinline__ float dot4(float4 a, float4 b) {
    return a.x * b.x + a.y * b.y + a.z * b.z + a.w * b.w;
}
__device__ __forceinline__ bf16x8 pack8(const float4 f0, const float4 f1) {
    union { unsigned short u[8]; bf16x8 v; } r;
    r.u[0] = f2bf(f0.x); r.u[1] = f2bf(f0.y); r.u[2] = f2bf(f0.z); r.u[3] = f2bf(f0.w);
    r.u[4] = f2bf(f1.x); r.u[5] = f2bf(f1.y); r.u[6] = f2bf(f1.z); r.u[7] = f2bf(f1.w);
    return r.v;
}

// Single cooperative kernel, grid = 256 blocks (1/CU), block = (b, dc) with
// b = idx&31 (XCD-local: XCD = idx%8 = b%8 -> emb gather L2-local),
// dc = idx>>5 in 0..7 = 32-column chunk of both Wl and Wr.
// Phase A: 128x(32+32) GEMM slice via 16x16x32 bf16 MFMA; A gathered from emb
//   and W cast fp32->bf16 in-register; fp32+bias -> padded LDS (stride 33).
// Phase B: pooled[b,d] = 0.5*(S*(sum_j xl + sum_i xr) + sum_ij |xl_j+xr_i|),
//   written into d_out as staging (out == pooled buffer, exactly B*D fp32).
// grid.sync()
// Phase C: out[b,d] = sum_k pooled[b,k]*Wrn[d,k] + S*S*brn[d], computed into
//   registers by the same (b,dc) block (reads full row, writes its 32 cols);
//   second grid.sync() separates all row-reads from the in-place writes.
__global__ __launch_bounds__(256) void k_all(
    const int* __restrict__ X, const float* __restrict__ emb,
    const float* __restrict__ Wl, const float* __restrict__ Wr,
    const float* __restrict__ bl, const float* __restrict__ br,
    const float* __restrict__ Wrn, const float* __restrict__ brn,
    float* __restrict__ out)
{
    constexpr int LP = 33;               // padded LDS row stride (floats)
    __shared__ float lxl[S * LP];        // 16896 B
    __shared__ float lxr[S * LP];        // 16896 B
    __shared__ float red[256];
    __shared__ float sxl_s[32];
    __shared__ float lp[D];

    const int b   = blockIdx.x & 31;
    const int dc  = blockIdx.x >> 5;     // 0..7
    const int cl  = dc * 32;
    const int tid = threadIdx.x;
    const int w   = tid >> 6;            // wave 0..3
    const int l   = tid & 63;
    const int lm  = l & 15;
    const int lq  = l >> 4;

    // ---- Phase A: GEMM. Wave w owns rows w*32..w*32+31 (2 row-tiles). ----
    const int r0 = w * 32 + lm;
    const int tok0 = X[b * S + r0];
    const int tok1 = X[b * S + r0 + 16];
    const float* a0 = emb + (size_t)tok0 * D;
    const float* a1 = emb + (size_t)tok1 * D;
    // B fragments: ct0/1 = Wl cols cl+{0..15},{16..31}; ct2/3 = Wr same.
    const float* bp0 = Wl + (size_t)(cl + lm) * D + lq * 8;
    const float* bp1 = Wl + (size_t)(cl + 16 + lm) * D + lq * 8;
    const float* bp2 = Wr + (size_t)(cl + lm) * D + lq * 8;
    const float* bp3 = Wr + (size_t)(cl + 16 + lm) * D + lq * 8;

    f32x4 acc[2][4];
#pragma unroll
    for (int rt = 0; rt < 2; ++rt)
#pragma unroll
        for (int ct = 0; ct < 4; ++ct)
            acc[rt][ct] = (f32x4){0.f, 0.f, 0.f, 0.f};

#pragma unroll
    for (int ks = 0; ks < 8; ++ks) {
        const int k0 = ks * 32 + lq * 8;
        const bf16x8 af0 = pack8(*(const float4*)(a0 + k0),
                                 *(const float4*)(a0 + k0 + 4));
        const bf16x8 af1 = pack8(*(const float4*)(a1 + k0),
                                 *(const float4*)(a1 + k0 + 4));
        const bf16x8 b0 = pack8(*(const float4*)(bp0 + ks * 32),
                                *(const float4*)(bp0 + ks * 32 + 4));
        const bf16x8 b1 = pack8(*(const float4*)(bp1 + ks * 32),
                                *(const float4*)(bp1 + ks * 32 + 4));
        const bf16x8 b2 = pack8(*(const float4*)(bp2 + ks * 32),
                                *(const float4*)(bp2 + ks * 32 + 4));
        const bf16x8 b3 = pack8(*(const float4*)(bp3 + ks * 32),
                                *(const float4*)(bp3 + ks * 32 + 4));
        acc[0][0] = __builtin_amdgcn_mfma_f32_16x16x32_bf16(af0, b0, acc[0][0], 0, 0, 0);
        acc[1][0] = __builtin_amdgcn_mfma_f32_16x16x32_bf16(af1, b0, acc[1][0], 0, 0, 0);
        acc[0][1] = __builtin_amdgcn_mfma_f32_16x16x32_bf16(af0, b1, acc[0][1], 0, 0, 0);
        acc[1][1] = __builtin_amdgcn_mfma_f32_16x16x32_bf16(af1, b1, acc[1][1], 0, 0, 0);
        acc[0][2] = __builtin_amdgcn_mfma_f32_16x16x32_bf16(af0, b2, acc[0][2], 0, 0, 0);
        acc[1][2] = __builtin_amdgcn_mfma_f32_16x16x32_bf16(af1, b2, acc[1][2], 0, 0, 0);
        acc[0][3] = __builtin_amdgcn_mfma_f32_16x16x32_bf16(af0, b3, acc[0][3], 0, 0, 0);
        acc[1][3] = __builtin_amdgcn_mfma_f32_16x16x32_bf16(af1, b3, acc[1][3], 0, 0, 0);
    }

    // Epilogue: C layout col=lane&15, row=(lane>>4)*4+i. fp32 + bias -> LDS.
    {
        const float bv[4] = { bl[cl + lm], bl[cl + 16 + lm],
                              br[cl + lm], br[cl + 16 + lm] };
#pragma unroll
        for (int ct = 0; ct < 4; ++ct) {
            float* dst = (ct < 2) ? lxl : lxr;
            const int c = (ct & 1) * 16 + lm;
#pragma unroll
            for (int rt = 0; rt < 2; ++rt) {
#pragma unroll
                for (int i = 0; i < 4; ++i) {
                    const int row = w * 32 + rt * 16 + lq * 4 + i;
                    dst[row * LP + c] = acc[rt][ct][i] + bv[ct];
                }
            }
        }
    }
    __syncthreads();

    // ---- Phase B: pairsum over fp32 LDS. 32 cols x 8 i-groups of 16. ----
    const int dl = tid & 31;
    const int ig = tid >> 5;             // 0..7

    float xr[16];
    float sr = 0.f;
#pragma unroll
    for (int u = 0; u < 16; ++u) {
        xr[u] = lxr[(ig * 16 + u) * LP + dl];
        sr += xr[u];
    }

    float sa[16];
#pragma unroll
    for (int u = 0; u < 16; ++u) sa[u] = 0.f;
    float sxl = 0.f;
#pragma unroll 4
    for (int j = 0; j < S; ++j) {
        const float x = lxl[j * LP + dl];
        sxl += x;
#pragma unroll
        for (int u = 0; u < 16; ++u)
            sa[u] += fabsf(x + xr[u]);   // 16 independent chains
    }
    float sabs = (((sa[0] + sa[1]) + (sa[2] + sa[3]))
                + ((sa[4] + sa[5]) + (sa[6] + sa[7])))
               + (((sa[8] + sa[9]) + (sa[10] + sa[11]))
                + ((sa[12] + sa[13]) + (sa[14] + sa[15])));

    red[tid] = sabs + (float)S * sr;
    if (ig == 0) sxl_s[dl] = sxl;
    __syncthreads();

    if (tid < 32) {
        float tot = 0.f;
#pragma unroll
        for (int g = 0; g < 8; ++g) tot += red[g * 32 + tid];
        out[(size_t)b * D + cl + tid] =
            0.5f * ((float)S * sxl_s[tid] + tot);
    }

    __threadfence();
    cg::this_grid().sync();

    // ---- Phase C: out[b,d] = pooled[b,:] . Wrn[d,:] + S*S*brn[d] ----
    lp[tid] = out[(size_t)b * D + tid];
    __syncthreads();

    const int kg = tid >> 5;
    const int d  = cl + dl;
    const float4* __restrict__ w4 = (const float4*)(Wrn + (size_t)d * D) + kg * 8;
    const float4* __restrict__ p4 = (const float4*)lp + kg * 8;
    float acc2 = 0.f;
#pragma unroll
    for (int f = 0; f < 8; ++f) acc2 += dot4(w4[f], p4[f]);

    red[tid] = acc2;
    __syncthreads();

    float res = 0.f;
    if (tid < 32) {
        float s2 = 0.f;
#pragma unroll
        for (int g = 0; g < 8; ++g) s2 += red[g * 32 + tid];
        res = s2 + (float)(S * S) * brn[cl + tid];
    }

    // all row-reads complete before any in-place write
    __threadfence();
    cg::this_grid().sync();

    if (tid < 32) out[(size_t)b * D + cl + tid] = res;
}

extern "C" void kernel_launch(void* const* d_in, const int* in_sizes, int n_in,
                              void* d_out, int out_size, void* d_ws, size_t ws_size,
                              hipStream_t stream) {
    const int*   X   = (const int*)d_in[0];
    const float* emb = (const float*)d_in[1];
    const float* Wl  = (const float*)d_in[2];
    const float* bl  = (const float*)d_in[3];
    const float* Wr  = (const float*)d_in[4];
    const float* br  = (const float*)d_in[5];
    const float* Wrn = (const float*)d_in[6];
    const float* brn = (const float*)d_in[7];
    float* out = (float*)d_out;

    void* args[] = { (void*)&X, (void*)&emb, (void*)&Wl, (void*)&Wr,
                     (void*)&bl, (void*)&br, (void*)&Wrn, (void*)&brn,
                     (void*)&out };
    hipLaunchCooperativeKernel((const void*)k_all, dim3(B * 8), dim3(256),
                               args, 0, stream);
}

// Round 4
// 108.521 us; speedup vs baseline: 2.0095x; 2.0095x over previous
//
#include <hip/hip_runtime.h>

#define D 256
#define S 128
#define B 32

typedef __attribute__((ext_vector_type(8))) short bf16x8;
typedef __attribute__((ext_vector_type(4))) float f32x4;

__device__ __forceinline__ unsigned short f2bf(float f) {
    union { float f; unsigned u; } v; v.f = f;
    unsigned r = v.u + 0x7FFFu + ((v.u >> 16) & 1u);   // RNE
    return (unsigned short)(r >> 16);
}
__device__ __forceinline__ float dot4(float4 a, float4 b) {
    return a.x * b.x + a.y * b.y + a.z * b.z + a.w * b.w;
}

// K0: one pass, two jobs.
//  tasks 0..262143  : Ab[r][c4..c4+3] = bf16(emb[X[r]][c4..c4+3]), r in 0..4095
//  tasks 262144..294911 : Wb[n][c4..] = bf16(n<256 ? Wl[n] : Wr[n-256])
// All loads float4-coalesced within a row; stores ushort4.
__global__ __launch_bounds__(256) void k0_prep(
    const int* __restrict__ X, const float* __restrict__ emb,
    const float* __restrict__ Wl, const float* __restrict__ Wr,
    unsigned short* __restrict__ Ab, unsigned short* __restrict__ Wb)
{
    const int task = blockIdx.x * 256 + threadIdx.x;
    const float* src;
    unsigned short* dst;
    if (task < 262144) {
        const int row = task >> 6;
        const int c4  = (task & 63) * 4;
        const int tok = X[row];
        src = emb + (size_t)tok * D + c4;
        dst = Ab + (size_t)row * D + c4;
    } else {
        const int t  = task - 262144;
        const int n  = t >> 6;
        const int c4 = (t & 63) * 4;
        src = (n < 256) ? (Wl + (size_t)n * D + c4)
                        : (Wr + (size_t)(n - 256) * D + c4);
        dst = Wb + (size_t)n * D + c4;
    }
    const float4 f = *(const float4*)src;
    ushort4 h;
    h.x = f2bf(f.x); h.y = f2bf(f.y); h.z = f2bf(f.z); h.w = f2bf(f.w);
    *(ushort4*)dst = h;
}

// K1 (fused GEMM + pairsum): one block per (b, dc-chunk of 16 d's), grid 512.
// b = idx&31 (XCD-local emb/Ab reuse), dc = idx>>5 in 0..15.
// Phase A: 128x(16+16) slice of Xl,Xr via 16x16x32 bf16 MFMA. A and B frags
//   are direct bf16x8 loads from pre-cast Ab/Wb (no f2bf here, no A staging).
//   fp32 acc + bias -> padded LDS (stride 17, conflict-free reads).
// Phase B: pooled[b,d] = 0.5*( S*(sum_j xl + sum_i xr) + sum_ij |xl_j+xr_i| )
//   with 8 independent |.| chains per thread.
__global__ __launch_bounds__(256) void k1_fused(
    const unsigned short* __restrict__ Ab, const unsigned short* __restrict__ Wb,
    const float* __restrict__ bl, const float* __restrict__ br,
    float* __restrict__ pooled)
{
    constexpr int LP = 17;               // padded LDS row stride (floats)
    __shared__ float lxl[S * LP];        // 8704 B
    __shared__ float lxr[S * LP];        // 8704 B
    __shared__ float red[256];

    const int b   = blockIdx.x & 31;
    const int dc  = blockIdx.x >> 5;     // 0..15
    const int cl  = dc * 16;
    const int tid = threadIdx.x;
    const int w   = tid >> 6;            // wave 0..3
    const int l   = tid & 63;
    const int lm  = l & 15;
    const int lq  = l >> 4;

    // ---- Phase A ----
    const int r0 = w * 32 + lm;          // row-tile 0 row (m = lm)
    const unsigned short* a0 = Ab + (size_t)(b * S + r0) * D + lq * 8;
    const unsigned short* a1 = a0 + (size_t)16 * D;
    const unsigned short* bp_l = Wb + (size_t)(cl + lm) * D + lq * 8;
    const unsigned short* bp_r = bp_l + (size_t)256 * D;

    f32x4 acc[2][2];
#pragma unroll
    for (int rt = 0; rt < 2; ++rt)
#pragma unroll
        for (int ct = 0; ct < 2; ++ct)
            acc[rt][ct] = (f32x4){0.f, 0.f, 0.f, 0.f};

#pragma unroll
    for (int ks = 0; ks < 8; ++ks) {
        const bf16x8 af0 = *(const bf16x8*)(a0 + ks * 32);
        const bf16x8 af1 = *(const bf16x8*)(a1 + ks * 32);
        const bf16x8 bfl = *(const bf16x8*)(bp_l + ks * 32);
        const bf16x8 bfr = *(const bf16x8*)(bp_r + ks * 32);
        acc[0][0] = __builtin_amdgcn_mfma_f32_16x16x32_bf16(af0, bfl, acc[0][0], 0, 0, 0);
        acc[1][0] = __builtin_amdgcn_mfma_f32_16x16x32_bf16(af1, bfl, acc[1][0], 0, 0, 0);
        acc[0][1] = __builtin_amdgcn_mfma_f32_16x16x32_bf16(af0, bfr, acc[0][1], 0, 0, 0);
        acc[1][1] = __builtin_amdgcn_mfma_f32_16x16x32_bf16(af1, bfr, acc[1][1], 0, 0, 0);
    }

    // Epilogue: C layout col=lane&15, row=(lane>>4)*4+i. fp32 + bias -> LDS.
    {
        const float bvl = bl[cl + lm];
        const float bvr = br[cl + lm];
#pragma unroll
        for (int rt = 0; rt < 2; ++rt) {
#pragma unroll
            for (int i = 0; i < 4; ++i) {
                const int row = w * 32 + rt * 16 + lq * 4 + i;
                lxl[row * LP + lm] = acc[rt][0][i] + bvl;
                lxr[row * LP + lm] = acc[rt][1][i] + bvr;
            }
        }
    }
    __syncthreads();

    // ---- Phase B: pairsum over fp32 LDS ----
    const int dl = tid & 15;
    const int ig = tid >> 4;             // 0..15, 8 i's each

    float xr[8];
    float sr = 0.f;
#pragma unroll
    for (int u = 0; u < 8; ++u) {
        xr[u] = lxr[(ig * 8 + u) * LP + dl];
        sr += xr[u];
    }

    float sa[8];
#pragma unroll
    for (int u = 0; u < 8; ++u) sa[u] = 0.f;
    float sxl = 0.f;
#pragma unroll 4
    for (int j = 0; j < S; ++j) {
        const float x = lxl[j * LP + dl];
        sxl += x;
#pragma unroll
        for (int u = 0; u < 8; ++u)
            sa[u] += fabsf(x + xr[u]);   // 8 independent chains
    }
    float sabs = ((sa[0] + sa[1]) + (sa[2] + sa[3]))
               + ((sa[4] + sa[5]) + (sa[6] + sa[7]));

    red[tid] = sabs + (float)S * sr;
    __syncthreads();

    if (tid < 16) {
        float tot = 0.f;
#pragma unroll
        for (int g = 0; g < 16; ++g) tot += red[g * 16 + tid];
        pooled[(size_t)b * D + cl + tid] =
            0.5f * ((float)S * sxl + tot);
    }
}

// K2: out[bb,d] = sum_k pooled[bb,k]*Wrn[d,k] + S*S*brn[d]
__global__ __launch_bounds__(256) void k2_out(
    const float* __restrict__ pooled, const float* __restrict__ Wrn,
    const float* __restrict__ brn, float* __restrict__ out)
{
    __shared__ float lp[D];
    __shared__ float red[256];
    const int bb = blockIdx.x >> 3;
    const int dc = blockIdx.x & 7;
    const int tid = threadIdx.x;
    lp[tid] = pooled[(size_t)bb * D + tid];
    __syncthreads();

    const int dl = tid & 31;
    const int kg = tid >> 5;
    const int d = dc * 32 + dl;
    const float4* __restrict__ w4 = (const float4*)(Wrn + (size_t)d * D) + kg * 8;
    const float4* __restrict__ p4 = (const float4*)lp + kg * 8;
    float acc = 0.f;
#pragma unroll
    for (int f = 0; f < 8; ++f) acc += dot4(w4[f], p4[f]);

    red[tid] = acc;
    __syncthreads();
    if (tid < 32) {
        float s = 0.f;
#pragma unroll
        for (int g = 0; g < 8; ++g) s += red[g * 32 + tid];
        out[(size_t)bb * D + dc * 32 + tid] = s + (float)(S * S) * brn[dc * 32 + tid];
    }
}

extern "C" void kernel_launch(void* const* d_in, const int* in_sizes, int n_in,
                              void* d_out, int out_size, void* d_ws, size_t ws_size,
                              hipStream_t stream) {
    const int*   X   = (const int*)d_in[0];
    const float* emb = (const float*)d_in[1];
    const float* Wl  = (const float*)d_in[2];
    const float* bl  = (const float*)d_in[3];
    const float* Wr  = (const float*)d_in[4];
    const float* br  = (const float*)d_in[5];
    const float* Wrn = (const float*)d_in[6];
    const float* brn = (const float*)d_in[7];
    float* out = (float*)d_out;

    // workspace layout
    unsigned short* Ab = (unsigned short*)d_ws;                 // 4096*256 bf16 = 2 MB
    unsigned short* Wb = Ab + (size_t)B * S * D;                // 512*256 bf16 = 256 KB
    float* pooled      = (float*)(Wb + (size_t)512 * D);        // 32 KB

    k0_prep<<<1152, 256, 0, stream>>>(X, emb, Wl, Wr, Ab, Wb);
    k1_fused<<<B * (D / 16), 256, 0, stream>>>(Ab, Wb, bl, br, pooled);
    k2_out<<<B * 8, 256, 0, stream>>>(pooled, Wrn, brn, out);
}